// Round 1
// baseline (454.455 us; speedup 1.0000x reference)
//
#include <hip/hip_runtime.h>

// LoKr: out = x @ (W + 2*scalar*(A kron B))^T  with B (16,1)
// => out[m,r] = (x@W^T)[m,r] + 2*scalar*B[r&15] * (x@A^T)[m, r>>4]
//
// R3: barrier-free streaming GEMM.
//  - grid = 256 blocks (1 per CU), 512 threads (8 waves).
//  - block b owns out cols [32b, 32b+32); wave w owns K-chunk [1024w, 1024w+1024).
//    Waves split K (not m), so each W element is consumed by exactly one wave:
//    W goes global -> VGPR directly in MFMA B-layout (16 rows x 128B contiguous
//    per load group => fully coalesced), fp32->bf16 converted in registers.
//    No LDS staging, no __syncthreads in the K-loop. W read exactly once.
//  - y2 = x@A^T folded in as a 3rd MFMA per m-frag with a broadcast B-frag:
//    cols 0-7 = A row 2b, cols 8-15 = A row 2b+1 (one __shfl in epilogue).
//  - Epilogue: 2-pass LDS reduction (64 KB) of the 8 waves' K-partials,
//    out written directly: no fp32 partials to HBM, no reduce kernel.

#define M_DIM 128
#define N_DIM 8192
#define K_DIM 8192
#define BN 32
#define NWAVE 8
#define KW (K_DIM / NWAVE)   // 1024 k per wave

typedef __attribute__((ext_vector_type(8))) short bf16x8;   // 8 bf16 = 4 VGPRs
typedef __attribute__((ext_vector_type(4))) float f32x4;    // MFMA acc

__device__ __forceinline__ unsigned short f2bf(float f) {
  unsigned u = __builtin_bit_cast(unsigned, f);
  u += 0x7FFFu + ((u >> 16) & 1u);   // round-to-nearest-even
  return (unsigned short)(u >> 16);
}

__device__ __forceinline__ bf16x8 cvt8(float4 a, float4 b) {
  bf16x8 r;
  r[0] = (short)f2bf(a.x); r[1] = (short)f2bf(a.y);
  r[2] = (short)f2bf(a.z); r[3] = (short)f2bf(a.w);
  r[4] = (short)f2bf(b.x); r[5] = (short)f2bf(b.y);
  r[6] = (short)f2bf(b.z); r[7] = (short)f2bf(b.w);
  return r;
}

__global__ void convert_x_kernel(const float4* __restrict__ x4,
                                 ushort4* __restrict__ xb4) {
  int t = blockIdx.x * blockDim.x + threadIdx.x;
  const int n4 = M_DIM * K_DIM / 4;  // 262144
  for (int i = t; i < n4; i += gridDim.x * blockDim.x) {
    float4 v = x4[i];
    ushort4 o;
    o.x = f2bf(v.x); o.y = f2bf(v.y); o.z = f2bf(v.z); o.w = f2bf(v.w);
    xb4[i] = o;
  }
}

__global__ __launch_bounds__(512, 2) void lokr_main(
    const float* __restrict__ W,           // 8192 x 8192
    const float* __restrict__ A,           // 512 x 8192
    const float* __restrict__ Bv,          // 16
    const float* __restrict__ scal,        // 1
    const unsigned short* __restrict__ xb, // x as bf16, 128 x 8192
    float* __restrict__ out)               // 128 x 8192 fp32
{
  __shared__ float red[NWAVE * M_DIM * 16];  // 64 KB reduction tile

  const int t    = threadIdx.x;
  const int lane = t & 63;
  const int wv   = t >> 6;          // wave 0..7 -> K-chunk
  const int b    = blockIdx.x;      // n-tile 0..255 (32 cols each)
  const int l15  = lane & 15;
  const int l4   = lane >> 4;
  const int kw   = wv * KW;

  const float sB = 2.0f * scal[0] * Bv[l15];

  f32x4 accW[8][2];   // [m-frag][n-frag]
  f32x4 accY[8];      // broadcast-A accumulator (cols 0-7: row 2b, 8-15: 2b+1)
  const f32x4 z4 = {0.f, 0.f, 0.f, 0.f};
#pragma unroll
  for (int mf = 0; mf < 8; ++mf) {
    accY[mf] = z4;
    accW[mf][0] = z4;
    accW[mf][1] = z4;
  }

  // per-lane base pointers (MFMA B-layout: lane l -> row (l&15), k-slice (l>>4)*8)
  const float* Wp = W + (size_t)(b * BN + l15) * K_DIM + kw + l4 * 8;
  const float* Ap = A + (size_t)(2 * b + (l15 >> 3)) * K_DIM + kw + l4 * 8;
  const unsigned short* xp = xb + (size_t)l15 * K_DIM + kw + l4 * 8;

  // ---- prologue: load k-step 0 ----
  float4 wr[2][2][2];   // [n-frag][kk][half]
  float4 ar[2][2];      // [kk][half]
#pragma unroll
  for (int nf = 0; nf < 2; ++nf)
#pragma unroll
    for (int kk = 0; kk < 2; ++kk)
#pragma unroll
      for (int h = 0; h < 2; ++h)
        wr[nf][kk][h] = *(const float4*)(Wp + (size_t)nf * 16 * K_DIM + kk * 32 + h * 4);
#pragma unroll
  for (int kk = 0; kk < 2; ++kk)
#pragma unroll
    for (int h = 0; h < 2; ++h)
      ar[kk][h] = *(const float4*)(Ap + kk * 32 + h * 4);

  for (int kt = 0; kt < KW; kt += 64) {
    // convert current W/A regs -> bf16 fragments
    bf16x8 wbf[2][2], abf[2];
#pragma unroll
    for (int nf = 0; nf < 2; ++nf)
#pragma unroll
      for (int kk = 0; kk < 2; ++kk)
        wbf[nf][kk] = cvt8(wr[nf][kk][0], wr[nf][kk][1]);
#pragma unroll
    for (int kk = 0; kk < 2; ++kk)
      abf[kk] = cvt8(ar[kk][0], ar[kk][1]);

    // prefetch next iteration's W/A (HBM latency hides under MFMA phase)
    if (kt + 64 < KW) {
#pragma unroll
      for (int nf = 0; nf < 2; ++nf)
#pragma unroll
        for (int kk = 0; kk < 2; ++kk)
#pragma unroll
          for (int h = 0; h < 2; ++h)
            wr[nf][kk][h] = *(const float4*)(Wp + (size_t)nf * 16 * K_DIM + kt + 64 + kk * 32 + h * 4);
#pragma unroll
      for (int kk = 0; kk < 2; ++kk)
#pragma unroll
        for (int h = 0; h < 2; ++h)
          ar[kk][h] = *(const float4*)(Ap + kt + 64 + kk * 32 + h * 4);
    }

    // MFMA phase: x fragments from global (L2-resident bf16 copy)
#pragma unroll
    for (int kk = 0; kk < 2; ++kk) {
      bf16x8 xa[8];
#pragma unroll
      for (int mf = 0; mf < 8; ++mf)
        xa[mf] = *(const bf16x8*)(xp + (size_t)mf * 16 * K_DIM + kt + kk * 32);
#pragma unroll
      for (int mf = 0; mf < 8; ++mf) {
        accW[mf][0] = __builtin_amdgcn_mfma_f32_16x16x32_bf16(xa[mf], wbf[0][kk], accW[mf][0], 0, 0, 0);
        accW[mf][1] = __builtin_amdgcn_mfma_f32_16x16x32_bf16(xa[mf], wbf[1][kk], accW[mf][1], 0, 0, 0);
        accY[mf]    = __builtin_amdgcn_mfma_f32_16x16x32_bf16(xa[mf], abf[kk],    accY[mf],    0, 0, 0);
      }
    }
  }

  // ---- epilogue: combine y2, reduce 8 K-partials via LDS, write out ----
  // C-layout: row m = mf*16 + (lane>>4)*4 + reg, col = lane&15.
  // accY col c holds y2[m, 2b + (c>>3)]; out col r = 32b + nf*16 + (l&15).
#pragma unroll 1
  for (int nf = 0; nf < 2; ++nf) {
    if (nf) __syncthreads();   // protect LDS reuse between passes
#pragma unroll
    for (int mf = 0; mf < 8; ++mf) {
#pragma unroll
      for (int r = 0; r < 4; ++r) {
        float y2v = __shfl(accY[mf][r], (lane & 48) | (nf << 3), 64);
        int m = mf * 16 + l4 * 4 + r;
        red[wv * 2048 + m * 16 + l15] = accW[mf][nf][r] + sB * y2v;
      }
    }
    __syncthreads();
    // 512 threads x 4 consecutive floats = the full 128x16 tile
    const float* rp = red + t * 4;
    float4 s = *(const float4*)rp;
#pragma unroll
    for (int w = 1; w < NWAVE; ++w) {
      float4 v = *(const float4*)(rp + w * 2048);
      s.x += v.x; s.y += v.y; s.z += v.z; s.w += v.w;
    }
    int m  = t >> 2;
    int c0 = (t & 3) * 4;
    *(float4*)(out + (size_t)m * N_DIM + b * BN + nf * 16 + c0) = s;
  }
}

extern "C" void kernel_launch(void* const* d_in, const int* in_sizes, int n_in,
                              void* d_out, int out_size, void* d_ws, size_t ws_size,
                              hipStream_t stream) {
  const float* x    = (const float*)d_in[0];   // 128 x 8192
  const float* W    = (const float*)d_in[1];   // 8192 x 8192
  const float* A    = (const float*)d_in[2];   // 512 x 8192
  const float* Bv   = (const float*)d_in[3];   // 16
  const float* scal = (const float*)d_in[4];   // 1
  float* out = (float*)d_out;

  // ws layout: [0, 2MB) x as bf16. (partials buffer eliminated)
  unsigned short* xb = (unsigned short*)d_ws;

  convert_x_kernel<<<512, 256, 0, stream>>>((const float4*)x, (ushort4*)xb);
  lokr_main<<<N_DIM / BN, 512, 0, stream>>>(W, A, Bv, scal, xb, out);
}

// Round 2
// 445.455 us; speedup vs baseline: 1.0202x; 1.0202x over previous
//
#include <hip/hip_runtime.h>

// LoKr: out = x @ (W + 2*scalar*(A kron B))^T  with B (16,1)
// => out[m,r] = (x@W^T)[m,r] + 2*scalar*B[r&15] * (x@A^T)[m, r>>4]
//
// R4: barrier-free streaming GEMM, register-pressure-fixed.
//  - grid = 256 blocks (1 per CU), 512 threads (8 waves).
//  - block b owns out cols [32b, 32b+32).
//  - waves split 2-way over m (64 rows each) x 4-way over K (2048 each).
//    R3 spilled (WRITE_SIZE 37MB vs 4MB expected -> ~33MB scratch): 8-way
//    K-split needed ~220 live regs. Halving acc (48) + 32-K-granular
//    ping-pong pipeline with STATIC buffer names fits ~180 unified regs.
//  - W global->VGPR in MFMA B-layout (16 rows x contiguous 32B/lane pair),
//    fp32->bf16 in registers, no LDS staging, no K-loop barriers.
//    Each W element read by the 2 mw-waves: 1st from HBM, 2nd hits L2.
//  - y2 = x@A^T folded as 3rd MFMA with broadcast A-frag (rows 2b, 2b+1).
//  - Epilogue: 2-pass LDS (32 KB) reduction over the 4 K-chunks, direct
//    fp32 out write. No partials in HBM, no reduce kernel.

#define M_DIM 128
#define N_DIM 8192
#define K_DIM 8192
#define BN 32
#define KWC (K_DIM / 4)   // 2048 k per K-chunk wave

typedef __attribute__((ext_vector_type(8))) short bf16x8;   // 8 bf16 = 4 VGPRs
typedef __attribute__((ext_vector_type(4))) float f32x4;    // MFMA acc

__device__ __forceinline__ unsigned short f2bf(float f) {
  unsigned u = __builtin_bit_cast(unsigned, f);
  u += 0x7FFFu + ((u >> 16) & 1u);   // round-to-nearest-even
  return (unsigned short)(u >> 16);
}

__device__ __forceinline__ bf16x8 cvt8(float4 a, float4 b) {
  bf16x8 r;
  r[0] = (short)f2bf(a.x); r[1] = (short)f2bf(a.y);
  r[2] = (short)f2bf(a.z); r[3] = (short)f2bf(a.w);
  r[4] = (short)f2bf(b.x); r[5] = (short)f2bf(b.y);
  r[6] = (short)f2bf(b.z); r[7] = (short)f2bf(b.w);
  return r;
}

__global__ void convert_x_kernel(const float4* __restrict__ x4,
                                 ushort4* __restrict__ xb4) {
  int t = blockIdx.x * blockDim.x + threadIdx.x;
  const int n4 = M_DIM * K_DIM / 4;  // 262144
  for (int i = t; i < n4; i += gridDim.x * blockDim.x) {
    float4 v = x4[i];
    ushort4 o;
    o.x = f2bf(v.x); o.y = f2bf(v.y); o.z = f2bf(v.z); o.w = f2bf(v.w);
    xb4[i] = o;
  }
}

// load one 32-K half-step: W frag rows (2 nf) + A broadcast frag
#define LOADW(koff, w, a) { \
    w[0] = *(const float4*)(Wp + (koff)); \
    w[1] = *(const float4*)(Wp + (koff) + 4); \
    w[2] = *(const float4*)(Wp + 16 * (size_t)K_DIM + (koff)); \
    w[3] = *(const float4*)(Wp + 16 * (size_t)K_DIM + (koff) + 4); \
    a[0] = *(const float4*)(Ap + (koff)); \
    a[1] = *(const float4*)(Ap + (koff) + 4); \
  }

#define LOADX(koff, x) { \
    x[0] = *(const bf16x8*)(xp + (koff)); \
    x[1] = *(const bf16x8*)(xp + 16 * (size_t)K_DIM + (koff)); \
    x[2] = *(const bf16x8*)(xp + 32 * (size_t)K_DIM + (koff)); \
    x[3] = *(const bf16x8*)(xp + 48 * (size_t)K_DIM + (koff)); \
  }

#define MFMA_STEP(x, w0, w1, ab) { \
    accW[0][0] = __builtin_amdgcn_mfma_f32_16x16x32_bf16(x[0], w0, accW[0][0], 0, 0, 0); \
    accW[0][1] = __builtin_amdgcn_mfma_f32_16x16x32_bf16(x[0], w1, accW[0][1], 0, 0, 0); \
    accY[0]    = __builtin_amdgcn_mfma_f32_16x16x32_bf16(x[0], ab, accY[0],    0, 0, 0); \
    accW[1][0] = __builtin_amdgcn_mfma_f32_16x16x32_bf16(x[1], w0, accW[1][0], 0, 0, 0); \
    accW[1][1] = __builtin_amdgcn_mfma_f32_16x16x32_bf16(x[1], w1, accW[1][1], 0, 0, 0); \
    accY[1]    = __builtin_amdgcn_mfma_f32_16x16x32_bf16(x[1], ab, accY[1],    0, 0, 0); \
    accW[2][0] = __builtin_amdgcn_mfma_f32_16x16x32_bf16(x[2], w0, accW[2][0], 0, 0, 0); \
    accW[2][1] = __builtin_amdgcn_mfma_f32_16x16x32_bf16(x[2], w1, accW[2][1], 0, 0, 0); \
    accY[2]    = __builtin_amdgcn_mfma_f32_16x16x32_bf16(x[2], ab, accY[2],    0, 0, 0); \
    accW[3][0] = __builtin_amdgcn_mfma_f32_16x16x32_bf16(x[3], w0, accW[3][0], 0, 0, 0); \
    accW[3][1] = __builtin_amdgcn_mfma_f32_16x16x32_bf16(x[3], w1, accW[3][1], 0, 0, 0); \
    accY[3]    = __builtin_amdgcn_mfma_f32_16x16x32_bf16(x[3], ab, accY[3],    0, 0, 0); \
  }

__global__ __launch_bounds__(512, 2) void lokr_main(
    const float* __restrict__ W,           // 8192 x 8192
    const float* __restrict__ A,           // 512 x 8192
    const float* __restrict__ Bv,          // 16
    const float* __restrict__ scal,        // 1
    const unsigned short* __restrict__ xb, // x as bf16, 128 x 8192
    float* __restrict__ out)               // 128 x 8192 fp32
{
  __shared__ float red[8 * 64 * 16];   // 32 KB reduction tile

  const int t    = threadIdx.x;
  const int lane = t & 63;
  const int wv   = t >> 6;          // wave 0..7
  const int kwi  = wv & 3;          // K-chunk index
  const int mw   = wv >> 2;         // m-half index
  const int b    = blockIdx.x;      // n-tile 0..255 (32 cols each)
  const int l15  = lane & 15;
  const int l4   = lane >> 4;
  const int kw   = kwi * KWC;

  const float sB = 2.0f * scal[0] * Bv[l15];

  f32x4 accW[4][2];   // [m-frag][n-frag]
  f32x4 accY[4];      // broadcast-A accumulator
  const f32x4 z4 = {0.f, 0.f, 0.f, 0.f};
#pragma unroll
  for (int mf = 0; mf < 4; ++mf) {
    accY[mf] = z4;
    accW[mf][0] = z4;
    accW[mf][1] = z4;
  }

  // per-lane bases (MFMA frag layout: lane l -> row (l&15), k-slice (l>>4)*8)
  const float* Wp = W + (size_t)(b * BN + l15) * K_DIM + kw + l4 * 8;
  const float* Ap = A + (size_t)(2 * b + (l15 >> 3)) * K_DIM + kw + l4 * 8;
  const unsigned short* xp = xb + (size_t)(mw * 64 + l15) * K_DIM + kw + l4 * 8;

  // ping-pong register buffers (static names - no runtime indexing)
  float4 wc[4], ac[2];    // current fp32 W/A half-step
  float4 wn[4], an[2];    // next
  bf16x8 xc[4], xn[4];    // current / next x fragments (L2-resident)

  // ---- prologue ----
  LOADW(0, wc, ac);
  LOADX(0, xc);

  for (int k = 0; k < KWC; k += 64) {
    // half A: compute k, prefetch k+32
    LOADW(k + 32, wn, an);
    {
      bf16x8 w0 = cvt8(wc[0], wc[1]);        // waits (counted) on wc batch
      bf16x8 w1 = cvt8(wc[2], wc[3]);
      bf16x8 ab = cvt8(ac[0], ac[1]);
      LOADX(k + 32, xn);
      MFMA_STEP(xc, w0, w1, ab);
    }
    // half B: compute k+32, prefetch k+64
    if (k + 64 < KWC) LOADW(k + 64, wc, ac);
    {
      bf16x8 w0 = cvt8(wn[0], wn[1]);
      bf16x8 w1 = cvt8(wn[2], wn[3]);
      bf16x8 ab = cvt8(an[0], an[1]);
      LOADX(k + 64, xc);   // last iter reads <=1.2KB past xb, inside ws: safe
      MFMA_STEP(xn, w0, w1, ab);
    }
  }

  // ---- epilogue: fold y2, reduce 4 K-partials via LDS, write out ----
  // C-layout: row = frag_row*16... m = mw*64 + mf*16 + l4*4 + r, col = l15.
  // accY cols 0-7 hold y2[m, 2b], cols 8-15 hold y2[m, 2b+1].
  float* redp = red + wv * 1024;
#pragma unroll 1
  for (int nf = 0; nf < 2; ++nf) {
    if (nf) __syncthreads();   // protect LDS reuse between passes
#pragma unroll
    for (int mf = 0; mf < 4; ++mf) {
#pragma unroll
      for (int r = 0; r < 4; ++r) {
        float y2v = __shfl(accY[mf][r], (lane & 48) | (nf << 3), 64);
        int mrel = mf * 16 + l4 * 4 + r;     // 0..63 within this mw half
        redp[mrel * 16 + l15] = accW[mf][nf][r] + sB * y2v;
      }
    }
    __syncthreads();
    // 512 threads x float4 = full 128x16 tile; sum the 4 K-chunk partials
    int m  = t >> 2;            // 0..127
    int c0 = (t & 3) * 4;
    const float* rp = red + (m >> 6) * 4096 + (m & 63) * 16 + c0;
    float4 s = *(const float4*)rp;
#pragma unroll
    for (int kp = 1; kp < 4; ++kp) {
      float4 v = *(const float4*)(rp + kp * 1024);
      s.x += v.x; s.y += v.y; s.z += v.z; s.w += v.w;
    }
    *(float4*)(out + (size_t)m * N_DIM + b * BN + nf * 16 + c0) = s;
  }
}

extern "C" void kernel_launch(void* const* d_in, const int* in_sizes, int n_in,
                              void* d_out, int out_size, void* d_ws, size_t ws_size,
                              hipStream_t stream) {
  const float* x    = (const float*)d_in[0];   // 128 x 8192
  const float* W    = (const float*)d_in[1];   // 8192 x 8192
  const float* A    = (const float*)d_in[2];   // 512 x 8192
  const float* Bv   = (const float*)d_in[3];   // 16
  const float* scal = (const float*)d_in[4];   // 1
  float* out = (float*)d_out;

  // ws layout: [0, 2MB) x as bf16
  unsigned short* xb = (unsigned short*)d_ws;

  convert_x_kernel<<<512, 256, 0, stream>>>((const float4*)x, (ushort4*)xb);
  lokr_main<<<N_DIM / BN, 512, 0, stream>>>(W, A, Bv, scal, xb, out);
}